// Round 13
// baseline (322.122 us; speedup 1.0000x reference)
//
#include <hip/hip_runtime.h>
#include <hip/hip_bf16.h>
#include <hip/hip_cooperative_groups.h>

namespace cg = cooperative_groups;

typedef unsigned int uint;
typedef unsigned short ushort;
typedef __attribute__((ext_vector_type(8))) short bf16x8;
typedef __attribute__((ext_vector_type(4))) float f32x4;

#define Tn 128
#define Bn 16
#define HH 128
#define G3 384
#define DIN 1024
#define PAD 136   // ushort row stride (272 B, 16B-aligned, breaks pow2 banks)
#define SQP 132   // SQ row stride in floats

#if __has_builtin(__builtin_amdgcn_cvt_pk_bf16_f32)
__device__ __forceinline__ uint pack2(float a, float b){
    auto v = __builtin_amdgcn_cvt_pk_bf16_f32(a, b);   // lo = a, hi = b, RNE
    union { decltype(v) v2; uint u; } c; c.v2 = v;
    return c.u;
}
#else
__device__ __forceinline__ ushort f2bf_(float f){
    union{float f; uint u;} c; c.f = f;
    uint u = c.u + 0x7fffu + ((c.u >> 16) & 1u);
    return (ushort)(u >> 16);
}
__device__ __forceinline__ uint pack2(float a, float b){
    return ((uint)f2bf_(b) << 16) | (uint)f2bf_(a);
}
#endif
__device__ __forceinline__ ushort f2bf(float f){ return (ushort)(pack2(f, f) & 0xffffu); }

#if __has_builtin(__builtin_amdgcn_fmed3f)
__device__ __forceinline__ float clampf(float x, float lo, float hi){
    return __builtin_amdgcn_fmed3f(x, lo, hi);
}
#else
__device__ __forceinline__ float clampf(float x, float lo, float hi){
    return fminf(hi, fmaxf(lo, x));
}
#endif

__device__ __forceinline__ float rcpf(float x){ return __builtin_amdgcn_rcpf(x); }
__device__ __forceinline__ float tanh_rat(float x){
    x = clampf(x, -5.f, 5.f);
    float t = x*x;
    float n = x*fmaf(t, fmaf(t, (t + 378.f), 17325.f), 135135.f);
    float d = fmaf(t, fmaf(t, fmaf(t, 28.f, 3150.f), 62370.f), 135135.f);
    return n * rcpf(d);
}
__device__ __forceinline__ float sig_num(float m, float t){
    return m*fmaf(t, fmaf(t, fmaf(t, 0.5f, 189.f), 8662.5f), 67567.5f);
}
__device__ __forceinline__ float sig_den(float t){
    return fmaf(t, fmaf(t, fmaf(t, 28.f, 3150.f), 62370.f), 135135.f);
}

// LDS-only barrier: leaves global prefetches (vmcnt) in flight.
__device__ __forceinline__ void bar_lds(){
    asm volatile("s_waitcnt lgkmcnt(0)\n\ts_barrier" ::: "memory");
}

// ---- phase-unioned LDS: embgi needs 43.5 KB, gru needs 24.9 KB
struct SmemEmb {
    ushort LX[16*PAD];     // x chunk bf16 (8 rows + 8 zero rows)
    ushort LW[128*PAD];    // weight chunk bf16
    ushort LE[16*PAD];     // emb bf16 (8 rows + 8 zero rows)
};
struct SmemGru {
    ushort HF[2][2048];    // h in B-frag order, dbuf
    ushort BFm[2][2048];   // wbeta in B-frag order, dbuf (GT1)
    float  SQ[16][SQP];    // [chain][k] s or q
};
union SmemU { SmemEmb e; SmemGru g; };

// ============ Phase 1: emb + Gi + WoE for this block's 8 rows.
// Single-buffered staging (fp32 -> bf16 inline: no k_cvt pre-pass), barriers
// unconditional so all 16 waves participate; threads >= 512 idle through them.
__device__ void embgi_phase(SmemU& sm, int tid,
    const float* __restrict__ x,    const float* __restrict__ Wemb,
    const float* __restrict__ Wiha, const float* __restrict__ Wihb,
    const float* __restrict__ biha, const float* __restrict__ bhha,
    const float* __restrict__ bihb, const float* __restrict__ bhhb,
    const float* __restrict__ Wo,
    float* __restrict__ gia, float* __restrict__ gib, float* __restrict__ woE,
    int blk)
{
    ushort* LX = sm.e.LX;
    ushort* LW = sm.e.LW;
    ushort* LE = sm.e.LE;
    int lane = tid & 63, wave = tid >> 6;
    int quad = lane >> 4, n = lane & 15;
    int R0 = blk * 8;
    bool act = tid < 512;
    int xr = tid >> 6, xc = (tid & 63) * 2;    // (act) x staging: 1 float2/thread
    int wr2 = tid >> 2, wc2 = (tid & 3) * 32;  // (act) W staging: 8 float4/thread

    // zero pad rows 8-15 of LX and LE
    if (tid < 544){
        ((uint*)&LX[8*PAD])[tid] = 0;
        ((uint*)&LE[8*PAD])[tid] = 0;
    }

    f32x4 acc = {0.f,0.f,0.f,0.f};
    // ---- emb = x @ Wemb^T over 8 K-chunks
    for (int kc = 0; kc < 8; ++kc){
        __syncthreads();
        if (act){
            float2 v = *(const float2*)(x + (size_t)(R0 + xr)*DIN + kc*128 + xc);
            *(uint*)&LX[xr*PAD + xc] = pack2(v.x, v.y);
            const float4* sw = (const float4*)(Wemb + (size_t)wr2*DIN + kc*128 + wc2);
            float4 g0=sw[0],g1=sw[1],g2=sw[2],g3=sw[3],g4=sw[4],g5=sw[5],g6=sw[6],g7=sw[7];
            uint4* dB = (uint4*)&LW[wr2*PAD + wc2];
            dB[0] = (uint4){pack2(g0.x,g0.y),pack2(g0.z,g0.w),pack2(g1.x,g1.y),pack2(g1.z,g1.w)};
            dB[1] = (uint4){pack2(g2.x,g2.y),pack2(g2.z,g2.w),pack2(g3.x,g3.y),pack2(g3.z,g3.w)};
            dB[2] = (uint4){pack2(g4.x,g4.y),pack2(g4.z,g4.w),pack2(g5.x,g5.y),pack2(g5.z,g5.w)};
            dB[3] = (uint4){pack2(g6.x,g6.y),pack2(g6.z,g6.w),pack2(g7.x,g7.y),pack2(g7.z,g7.w)};
        }
        __syncthreads();
        if (act){
#pragma unroll
            for (int kb = 0; kb < 4; ++kb){
                bf16x8 a = *(const bf16x8*)&LX[n*PAD + kb*32 + quad*8];
                bf16x8 b = *(const bf16x8*)&LW[(wave*16 + n)*PAD + kb*32 + quad*8];
                acc = __builtin_amdgcn_mfma_f32_16x16x32_bf16(a, b, acc, 0,0,0);
            }
        }
    }
    // epilogue: LE bf16 + WoE fp32 (valid rows m<8 -> quads 0,1)
    if (act && quad < 2){
        int e = wave*16 + n;
        float wo = Wo[e];
#pragma unroll
        for (int l = 0; l < 4; ++l){
            int m = quad*4 + l;
            LE[m*PAD + e] = f2bf(acc[l]);
            int row = R0 + m, b_ = row >> 7, pos = row & 127;
            woE[((size_t)(pos*Bn + b_))*HH + e] = wo * acc[l];
        }
    }
    // ---- Gi = emb @ Wih^T (+bias), 6 N-chunks; P-permuted, r/z pre-scaled 0.5
    for (int nc = 0; nc < 6; ++nc){
        int gband = (nc < 3) ? nc : nc - 3;
        __syncthreads();   // orders LE writes on nc==0; LW reuse after
        if (act){
            const float* Wsrc = (nc < 3) ? Wiha : Wihb;
            const float4* sw = (const float4*)(Wsrc + (size_t)(gband*128 + wr2)*HH + wc2);
            float4 g0=sw[0],g1=sw[1],g2=sw[2],g3=sw[3],g4=sw[4],g5=sw[5],g6=sw[6],g7=sw[7];
            uint4* dB = (uint4*)&LW[wr2*PAD + wc2];
            dB[0] = (uint4){pack2(g0.x,g0.y),pack2(g0.z,g0.w),pack2(g1.x,g1.y),pack2(g1.z,g1.w)};
            dB[1] = (uint4){pack2(g2.x,g2.y),pack2(g2.z,g2.w),pack2(g3.x,g3.y),pack2(g3.z,g3.w)};
            dB[2] = (uint4){pack2(g4.x,g4.y),pack2(g4.z,g4.w),pack2(g5.x,g5.y),pack2(g5.z,g5.w)};
            dB[3] = (uint4){pack2(g6.x,g6.y),pack2(g6.z,g6.w),pack2(g7.x,g7.y),pack2(g7.z,g7.w)};
        }
        __syncthreads();
        if (act){
            f32x4 gc = {0.f,0.f,0.f,0.f};
#pragma unroll
            for (int kb = 0; kb < 4; ++kb){
                bf16x8 a = *(const bf16x8*)&LE[n*PAD + kb*32 + quad*8];
                bf16x8 b = *(const bf16x8*)&LW[(wave*16 + n)*PAD + kb*32 + quad*8];
                gc = __builtin_amdgcn_mfma_f32_16x16x32_bf16(a, b, gc, 0,0,0);
            }
            int g = gband*128 + wave*16 + n;
            const float* bi = (nc < 3) ? biha : bihb;
            const float* bh = (nc < 3) ? bhha : bhhb;
            float bias = bi[g] + ((gband < 2) ? bh[g] : 0.f);
            float scale = (gband < 2) ? 0.5f : 1.f;
            float* dst = (nc < 3) ? gia : gib;
            int P = (3*wave + gband)*16 + n;
            if (quad < 2){
#pragma unroll
                for (int l = 0; l < 4; ++l){
                    int row = R0 + quad*4 + l, b_ = row >> 7, pos = row & 127;
                    dst[((size_t)(pos*Bn + b_))*G3 + P] = scale*(gc[l] + bias);
                }
            }
        }
    }
}

// ============ Phase 2: GRU recurrence (R11 champion body, verbatim semantics).
template<int GT>
__device__ void gru_phase(SmemU& sm,
    const float* __restrict__ Whh, const float* __restrict__ bhh,
    const float* __restrict__ Wsc, const float* __restrict__ bsc,
    const float* __restrict__ Gi,  const float* __restrict__ WoE,
    float* __restrict__ outW, int i)
{
    auto& HF  = sm.g.HF;
    auto& BFm = sm.g.BFm;
    auto& SQ  = sm.g.SQ;
    int tid = threadIdx.x;
    int lane = tid & 63, wave = tid >> 6;
    int quad = lane >> 4, n = lane & 15;

    if (tid < 256) ((uint4*)HF[1])[tid] = (uint4){0,0,0,0};

    if (wave < 8){
        // ================= G-waves: gates only =================
        int u = wave, jb = u*16 + quad*4;
        bf16x8 afr[3][4];
#pragma unroll
        for (int g = 0; g < 3; ++g){
            const float* src = Whh + (size_t)(g*HH + u*16 + n)*HH;
            float s = (g < 2) ? 0.5f : 1.0f;   // fold 0.5 into r,z rows
#pragma unroll
            for (int kb = 0; kb < 4; ++kb){
                const float* p = src + kb*32 + quad*8;
                float4 a = *(const float4*)p, b2 = *(const float4*)(p+4);
                union { uint4 q; bf16x8 v; } cv;
                cv.q.x = pack2(s*a.x, s*a.y);   cv.q.y = pack2(s*a.z, s*a.w);
                cv.q.z = pack2(s*b2.x,s*b2.y); cv.q.w = pack2(s*b2.z,s*b2.w);
                afr[g][kb] = cv.v;
            }
        }
        float bh2[4];
#pragma unroll
        for (int l = 0; l < 4; ++l) bh2[l] = bhh[2*HH + jb + l];
        float h4[4] = {0.f,0.f,0.f,0.f};

        const float* gp = Gi + ((size_t)(i*Bn + n))*G3 + u*48 + quad*4;
        float4 pg0 = *(const float4*)(gp);
        float4 pg1 = *(const float4*)(gp + 16);
        float4 pg2 = *(const float4*)(gp + 32);
        bar_lds();

        for (int k = 0; k <= i; ++k){
            int pos = i - k;
            float4 g0 = pg0, g1 = pg1, g2 = pg2;
            int pnext = (pos > 0) ? pos - 1 : 0;
            const float* gp2 = Gi + ((size_t)(pnext*Bn + n))*G3 + u*48 + quad*4;
            pg0 = *(const float4*)(gp2);
            pg1 = *(const float4*)(gp2 + 16);
            pg2 = *(const float4*)(gp2 + 32);

            const ushort* HR = HF[(k+1)&1];
            f32x4 a0={0.f,0.f,0.f,0.f}, a1=a0, a2=a0;
#pragma unroll
            for (int kb = 0; kb < 4; ++kb){
                bf16x8 bfr = *(const bf16x8*)&HR[(64*kb + lane)*8];
                a0 = __builtin_amdgcn_mfma_f32_16x16x32_bf16(afr[0][kb], bfr, a0, 0,0,0);
                a1 = __builtin_amdgcn_mfma_f32_16x16x32_bf16(afr[1][kb], bfr, a1, 0,0,0);
                a2 = __builtin_amdgcn_mfma_f32_16x16x32_bf16(afr[2][kb], bfr, a2, 0,0,0);
            }
            float gi0[4]={g0.x,g0.y,g0.z,g0.w};
            float gi1[4]={g1.x,g1.y,g1.z,g1.w};
            float gi2[4]={g2.x,g2.y,g2.z,g2.w};
#pragma unroll
            for (int l = 0; l < 4; ++l){
                float mr = clampf(gi0[l] + a0[l], -4.f, 4.f);
                float mz = clampf(gi1[l] + a1[l], -4.f, 4.f);
                float tr = mr*mr, tz = mz*mz;
                float nr = sig_num(mr, tr), nz = sig_num(mz, tz);
                float dr = sig_den(tr),     dz = sig_den(tz);
                float rD = rcpf(dr*dz);
                float r = fmaf(nr*dz, rD, 0.5f);
                float z = fmaf(nz*dr, rD, 0.5f);
                float nn = tanh_rat(gi2[l] + r*(a2[l] + bh2[l]));
                h4[l] = nn + z*(h4[l] - nn);
            }
            *(uint2*)&HF[k&1][((jb>>3)*16 + n)*8 + (jb&4)] =
                (uint2){pack2(h4[0],h4[1]), pack2(h4[2],h4[3])};
            bar_lds();
        }
        if (GT){ bar_lds(); bar_lds(); } else { bar_lds(); }
    } else {
        // ================= P-waves =================
        int u2 = wave - 8, jb = u2*16 + quad*4;
        if (GT){
            bf16x8 afr3[4];
#pragma unroll
            for (int kb = 0; kb < 4; ++kb){
                const float* p = Wsc + (size_t)(u2*16 + n)*HH + kb*32 + quad*8;
                float4 a = *(const float4*)p, b2 = *(const float4*)(p+4);
                union { uint4 q; bf16x8 v; } cv;
                cv.q.x = pack2(0.5f*a.x, 0.5f*a.y);  cv.q.y = pack2(0.5f*a.z, 0.5f*a.w);
                cv.q.z = pack2(0.5f*b2.x,0.5f*b2.y); cv.q.w = pack2(0.5f*b2.z,0.5f*b2.w);
                afr3[kb] = cv.v;
            }
            bf16x8 onesf;
            {
                union { uint4 q; bf16x8 v; } c1;
                uint o = (n == 0) ? 0x3F803F80u : 0u;
                c1.q = (uint4){o,o,o,o};
                onesf = c1.v;
            }
            float bb4[4];
#pragma unroll
            for (int l = 0; l < 4; ++l) bb4[l] = bsc[jb + l];
            float4 pwo = *(const float4*)(WoE + ((size_t)(i*Bn + n))*HH + jb);
            bar_lds();

            for (int k = 0; k <= i; ++k){
                int pos = i - k;
                float4 wo = pwo;
                pwo = *(const float4*)(WoE + ((size_t)(pos*Bn + n))*HH + jb);

                const ushort* HR = HF[(k+1)&1];
                f32x4 a3 = {0.f,0.f,0.f,0.f};
#pragma unroll
                for (int kb = 0; kb < 4; ++kb){
                    bf16x8 bfr = *(const bf16x8*)&HR[(64*kb + lane)*8];
                    a3 = __builtin_amdgcn_mfma_f32_16x16x32_bf16(afr3[kb], bfr, a3, 0,0,0);
                }
                if (u2 == 0 && k >= 2){   // q_{k-2} = ones . BF (written step k-1)
                    const ushort* BR = BFm[(k+1)&1];
                    f32x4 qa = {0.f,0.f,0.f,0.f};
#pragma unroll
                    for (int kb = 0; kb < 4; ++kb){
                        bf16x8 bq = *(const bf16x8*)&BR[(64*kb + lane)*8];
                        qa = __builtin_amdgcn_mfma_f32_16x16x32_bf16(onesf, bq, qa, 0,0,0);
                    }
                    if (lane < 16) SQ[lane][k-2] = qa[0];
                }
                if (k >= 1){
                    float w0 = tanh_rat(a3[0]+bb4[0])*wo.x;
                    float w1 = tanh_rat(a3[1]+bb4[1])*wo.y;
                    float w2 = tanh_rat(a3[2]+bb4[2])*wo.z;
                    float w3 = tanh_rat(a3[3]+bb4[3])*wo.w;
                    *(uint2*)&BFm[k&1][((jb>>3)*16 + n)*8 + (jb&4)] =
                        (uint2){pack2(w0,w1), pack2(w2,w3)};
                }
                bar_lds();
            }
            {   // tail: wbeta_i from h_i (HF[i&1]) with WoE[0] (in pwo)
                const ushort* HR = HF[i&1];
                f32x4 a3 = {0.f,0.f,0.f,0.f};
#pragma unroll
                for (int kb = 0; kb < 4; ++kb){
                    bf16x8 bfr = *(const bf16x8*)&HR[(64*kb + lane)*8];
                    a3 = __builtin_amdgcn_mfma_f32_16x16x32_bf16(afr3[kb], bfr, a3, 0,0,0);
                }
                float w0 = tanh_rat(a3[0]+bb4[0])*pwo.x;
                float w1 = tanh_rat(a3[1]+bb4[1])*pwo.y;
                float w2 = tanh_rat(a3[2]+bb4[2])*pwo.z;
                float w3 = tanh_rat(a3[3]+bb4[3])*pwo.w;
                *(uint2*)&BFm[(i+1)&1][((jb>>3)*16 + n)*8 + (jb&4)] =
                    (uint2){pack2(w0,w1), pack2(w2,w3)};
            }
            bar_lds();
            if (u2 == 0){
                if (i >= 1){
                    const ushort* BR = BFm[i&1];
                    f32x4 qa = {0.f,0.f,0.f,0.f};
#pragma unroll
                    for (int kb = 0; kb < 4; ++kb){
                        bf16x8 bq = *(const bf16x8*)&BR[(64*kb + lane)*8];
                        qa = __builtin_amdgcn_mfma_f32_16x16x32_bf16(onesf, bq, qa, 0,0,0);
                    }
                    if (lane < 16) SQ[lane][i-1] = qa[0];
                }
                {
                    const ushort* BR = BFm[(i+1)&1];
                    f32x4 qa = {0.f,0.f,0.f,0.f};
#pragma unroll
                    for (int kb = 0; kb < 4; ++kb){
                        bf16x8 bq = *(const bf16x8*)&BR[(64*kb + lane)*8];
                        qa = __builtin_amdgcn_mfma_f32_16x16x32_bf16(onesf, bq, qa, 0,0,0);
                    }
                    if (lane < 16) SQ[lane][i] = qa[0];
                }
            }
            bar_lds();
        } else {
            // GT0: wave 8 computes s_k = 0.5*Wa . h_k (A-row 0); waves 9-15 idle.
            if (u2 == 0){
                bf16x8 afr3[4];
#pragma unroll
                for (int kb = 0; kb < 4; ++kb){
                    const float* p = Wsc + kb*32 + quad*8;
                    float4 a = *(const float4*)p, b2 = *(const float4*)(p+4);
                    union { uint4 q; bf16x8 v; } cv;
                    if (n == 0){
                        cv.q.x = pack2(0.5f*a.x, 0.5f*a.y);  cv.q.y = pack2(0.5f*a.z, 0.5f*a.w);
                        cv.q.z = pack2(0.5f*b2.x,0.5f*b2.y); cv.q.w = pack2(0.5f*b2.z,0.5f*b2.w);
                    } else cv.q = (uint4){0,0,0,0};
                    afr3[kb] = cv.v;
                }
                float bav = bsc[0];
                bar_lds();
                for (int k = 0; k <= i; ++k){
                    if (k >= 1){
                        const ushort* HR = HF[(k+1)&1];
                        f32x4 a3 = {0.f,0.f,0.f,0.f};
#pragma unroll
                        for (int kb = 0; kb < 4; ++kb){
                            bf16x8 bfr = *(const bf16x8*)&HR[(64*kb + lane)*8];
                            a3 = __builtin_amdgcn_mfma_f32_16x16x32_bf16(afr3[kb], bfr, a3, 0,0,0);
                        }
                        if (lane < 16) SQ[lane][k-1] = a3[0] + bav;
                    }
                    bar_lds();
                }
                {
                    const ushort* HR = HF[i&1];
                    f32x4 a3 = {0.f,0.f,0.f,0.f};
#pragma unroll
                    for (int kb = 0; kb < 4; ++kb){
                        bf16x8 bfr = *(const bf16x8*)&HR[(64*kb + lane)*8];
                        a3 = __builtin_amdgcn_mfma_f32_16x16x32_bf16(afr3[kb], bfr, a3, 0,0,0);
                    }
                    if (lane < 16) SQ[lane][i] = a3[0] + bav;
                }
                bar_lds();
            } else {
                bar_lds();
                for (int k = 0; k <= i; ++k) bar_lds();
                bar_lds();
            }
        }
    }
    if (tid < 512){   // flush SQ -> global, coalesced float4 (out phase masks k > i)
        int cn = tid >> 5, k4 = (tid & 31) * 4;
        *(float4*)&outW[((size_t)(cn*Tn + i))*Tn + k4] = *(const float4*)&SQ[cn][k4];
    }
}

// ============ Phase 3: softmax(s) . q; waves 0-7 handle rows blk*8 + wave.
__device__ void out_phase(const float* __restrict__ sW, const float* __restrict__ qW,
                          const float* __restrict__ bo, float* __restrict__ out, int blk)
{
    int tid = threadIdx.x, lane = tid & 63, wave = tid >> 6;
    if (wave >= 8) return;
    int r = blk*8 + wave;
    int i = r & (Tn-1);
    const float* s = sW + (size_t)r*Tn;
    const float* q = qW + (size_t)r*Tn;
    float s0 = (lane     <= i) ? s[lane]      : -1e30f;
    float s1 = (64+lane  <= i) ? s[64+lane]   : -1e30f;
    float m = fmaxf(s0, s1);
#pragma unroll
    for (int off = 32; off; off >>= 1) m = fmaxf(m, __shfl_xor(m, off));
    float e0 = __expf(s0 - m), e1 = __expf(s1 - m);
    float q0 = (lane    <= i) ? q[lane]    : 0.f;
    float q1 = (64+lane <= i) ? q[64+lane] : 0.f;
    float num = e0*q0 + e1*q1, den = e0 + e1;
#pragma unroll
    for (int off = 32; off; off >>= 1){
        num += __shfl_xor(num, off);
        den += __shfl_xor(den, off);
    }
    if (lane == 0) out[r] = num/den + bo[0];
}

// ============ fused cooperative kernel: embgi | grid.sync | gru | grid.sync | out
__global__ __launch_bounds__(1024, 1) void k_fused(
    const float* __restrict__ x,     const float* __restrict__ Wemb,
    const float* __restrict__ Wih_a, const float* __restrict__ Whh_a,
    const float* __restrict__ bih_a, const float* __restrict__ bhh_a,
    const float* __restrict__ Wa,    const float* __restrict__ ba,
    const float* __restrict__ Wih_b, const float* __restrict__ Whh_b,
    const float* __restrict__ bih_b, const float* __restrict__ bhh_b,
    const float* __restrict__ Wb,    const float* __restrict__ bb,
    const float* __restrict__ Wo,    const float* __restrict__ bo,
    float* __restrict__ giA, float* __restrict__ giB, float* __restrict__ woE,
    float* __restrict__ sW,  float* __restrict__ qW,  float* __restrict__ out)
{
    __shared__ __align__(16) SmemU sm;
    int tid = threadIdx.x;
    int blk = blockIdx.x;

    embgi_phase(sm, tid, x, Wemb, Wih_a, Wih_b, bih_a, bhh_a, bih_b, bhh_b, Wo,
                giA, giB, woE, blk);
    cg::this_grid().sync();

    int i = Tn - 1 - (blk >> 1);
    if ((blk & 1) == 0) gru_phase<0>(sm, Whh_a, bhh_a, Wa, ba, giA, nullptr, sW, i);
    else                gru_phase<1>(sm, Whh_b, bhh_b, Wb, bb, giB, woE,    qW, i);
    cg::this_grid().sync();

    out_phase(sW, qW, bo, out, blk);
}

extern "C" void kernel_launch(void* const* d_in, const int* in_sizes, int n_in,
                              void* d_out, int out_size, void* d_ws, size_t ws_size,
                              hipStream_t stream) {
    const float* x     = (const float*)d_in[0];
    const float* Wemb  = (const float*)d_in[1];
    const float* Wih_a = (const float*)d_in[2];
    const float* Whh_a = (const float*)d_in[3];
    const float* bih_a = (const float*)d_in[4];
    const float* bhh_a = (const float*)d_in[5];
    const float* Wa    = (const float*)d_in[6];
    const float* ba    = (const float*)d_in[7];
    const float* Wih_b = (const float*)d_in[8];
    const float* Whh_b = (const float*)d_in[9];
    const float* bih_b = (const float*)d_in[10];
    const float* bhh_b = (const float*)d_in[11];
    const float* Wb    = (const float*)d_in[12];
    const float* bb    = (const float*)d_in[13];
    const float* Wo    = (const float*)d_in[14];
    const float* bo    = (const float*)d_in[15];

    const int NR = Bn*Tn;                            // 2048 rows
    float* giA = (float*)d_ws;                       // [pos][b][384] fp32, P-permuted, r/z pre-scaled
    float* giB = giA + (size_t)NR*G3;
    float* woE = giB + (size_t)NR*G3;                // [pos][b][128] fp32
    float* sW  = woE + (size_t)NR*HH;                // [b][i][k] fp32
    float* qW  = sW + (size_t)NR*Tn;
    float* out = (float*)d_out;

    void* args[] = {
        (void*)&x, (void*)&Wemb, (void*)&Wih_a, (void*)&Whh_a,
        (void*)&bih_a, (void*)&bhh_a, (void*)&Wa, (void*)&ba,
        (void*)&Wih_b, (void*)&Whh_b, (void*)&bih_b, (void*)&bhh_b,
        (void*)&Wb, (void*)&bb, (void*)&Wo, (void*)&bo,
        (void*)&giA, (void*)&giB, (void*)&woE, (void*)&sW, (void*)&qW, (void*)&out
    };
    hipLaunchCooperativeKernel((const void*)k_fused, dim3(256), dim3(1024),
                               args, 0, stream);
}

// Round 14
// 236.745 us; speedup vs baseline: 1.3606x; 1.3606x over previous
//
#include <hip/hip_runtime.h>
#include <hip/hip_bf16.h>

typedef unsigned int uint;
typedef unsigned short ushort;
typedef __attribute__((ext_vector_type(8))) short bf16x8;
typedef __attribute__((ext_vector_type(4))) float f32x4;
typedef __attribute__((ext_vector_type(2))) float f32x2;

#define Tn 128
#define Bn 16
#define HH 128
#define G3 384
#define DIN 1024
#define PAD 136   // ushort row stride (272 B, 16B-aligned, breaks pow2 banks)
#define SQP 132   // SQ row stride in floats

#if __has_builtin(__builtin_amdgcn_cvt_pk_bf16_f32)
__device__ __forceinline__ uint pack2(float a, float b){
    auto v = __builtin_amdgcn_cvt_pk_bf16_f32(a, b);   // lo = a, hi = b, RNE
    union { decltype(v) v2; uint u; } c; c.v2 = v;
    return c.u;
}
#else
__device__ __forceinline__ ushort f2bf_(float f){
    union{float f; uint u;} c; c.f = f;
    uint u = c.u + 0x7fffu + ((c.u >> 16) & 1u);
    return (ushort)(u >> 16);
}
__device__ __forceinline__ uint pack2(float a, float b){
    return ((uint)f2bf_(b) << 16) | (uint)f2bf_(a);
}
#endif
__device__ __forceinline__ ushort f2bf(float f){ return (ushort)(pack2(f, f) & 0xffffu); }

#if __has_builtin(__builtin_amdgcn_fmed3f)
__device__ __forceinline__ float clampf(float x, float lo, float hi){
    return __builtin_amdgcn_fmed3f(x, lo, hi);
}
#else
__device__ __forceinline__ float clampf(float x, float lo, float hi){
    return fminf(hi, fmaxf(lo, x));
}
#endif

__device__ __forceinline__ float rcpf(float x){ return __builtin_amdgcn_rcpf(x); }
__device__ __forceinline__ f32x2 clamp2(f32x2 x, float lo, float hi){
    f32x2 r; r.x = clampf(x.x, lo, hi); r.y = clampf(x.y, lo, hi); return r;
}
__device__ __forceinline__ f32x2 rcp2(f32x2 x){
    f32x2 r; r.x = rcpf(x.x); r.y = rcpf(x.y); return r;
}
// Padé(7,6) tanh on a pair (packed fp32 math)
__device__ __forceinline__ f32x2 tanh2(f32x2 x){
    x = clamp2(x, -5.f, 5.f);
    f32x2 t = x*x;
    f32x2 n = x*(t*(t*(t + 378.f) + 17325.f) + 135135.f);
    f32x2 d = t*(t*(t*28.f + 3150.f) + 62370.f) + 135135.f;
    return n * rcp2(d);
}
__device__ __forceinline__ float tanh_rat(float x){
    x = clampf(x, -5.f, 5.f);
    float t = x*x;
    float n = x*fmaf(t, fmaf(t, (t + 378.f), 17325.f), 135135.f);
    float d = fmaf(t, fmaf(t, fmaf(t, 28.f, 3150.f), 62370.f), 135135.f);
    return n * rcpf(d);
}

// LDS-only barrier: leaves global prefetches (vmcnt) in flight.
__device__ __forceinline__ void bar_lds(){
    asm volatile("s_waitcnt lgkmcnt(0)\n\ts_barrier" ::: "memory");
}

// ============ one-time fp32 -> bf16 weight conversion: Wemb | Wiha | Wihb
__global__ __launch_bounds__(256) void k_cvt(const float* __restrict__ wemb,
                                             const float* __restrict__ wiha,
                                             const float* __restrict__ wihb,
                                             ushort* __restrict__ dst){
    int idx = (blockIdx.x*256 + threadIdx.x)*8;
    const float* s; int off;
    if (idx < 131072){ s = wemb; off = idx; }
    else if (idx < 180224){ s = wiha; off = idx - 131072; }
    else { s = wihb; off = idx - 180224; }
    float4 f0 = *(const float4*)(s + off);
    float4 f1 = *(const float4*)(s + off + 4);
    *(uint4*)(dst + idx) = (uint4){pack2(f0.x,f0.y),pack2(f0.z,f0.w),
                                   pack2(f1.x,f1.y),pack2(f1.z,f1.w)};
}

// ============ fused emb + Gi + WoE (R11 double-buffered pipeline, unchanged).
__device__ __forceinline__ const uint4* stage_src(int c, const ushort* WembB,
                                                  const ushort* WihaB,
                                                  const ushort* WihbB,
                                                  int wr2, int wc2){
    if (c < 8)  return (const uint4*)(WembB + (size_t)wr2*DIN + c*128 + wc2);
    if (c < 11) return (const uint4*)(WihaB + (size_t)((c-8)*128 + wr2)*HH + wc2);
    return (const uint4*)(WihbB + (size_t)((c-11)*128 + wr2)*HH + wc2);
}

__global__ __launch_bounds__(512) void k_embgi(
    const float* __restrict__ x,      const ushort* __restrict__ WembB,
    const ushort* __restrict__ WihaB, const ushort* __restrict__ WihbB,
    const float* __restrict__ biha,   const float* __restrict__ bhha,
    const float* __restrict__ bihb,   const float* __restrict__ bhhb,
    const float* __restrict__ Wo,
    float* __restrict__ gia, float* __restrict__ gib, float* __restrict__ woE)
{
    __shared__ __align__(16) ushort LX[2][16*PAD];
    __shared__ __align__(16) ushort LW[2][128*PAD];
    __shared__ __align__(16) ushort LE[16*PAD];
    int tid = threadIdx.x;
    int lane = tid & 63, wave = tid >> 6;
    int quad = lane >> 4, n = lane & 15;
    int R0 = blockIdx.x * 8;
    int xr = tid >> 6, xc = (tid & 63) * 2;
    int wr2 = tid >> 2, wc2 = (tid & 3) * 32;

    for (int z = tid; z < 544; z += 512){
        ((uint*)&LX[0][8*PAD])[z] = 0;
        ((uint*)&LX[1][8*PAD])[z] = 0;
        ((uint*)&LE[8*PAD])[z]    = 0;
    }
    {
        const uint4* s0 = stage_src(0, WembB, WihaB, WihbB, wr2, wc2);
        uint4 a0=s0[0], a1=s0[1], a2=s0[2], a3=s0[3];
        float2 v = *(const float2*)(x + (size_t)(R0 + xr)*DIN + xc);
        uint4* d = (uint4*)&LW[0][wr2*PAD + wc2];
        d[0]=a0; d[1]=a1; d[2]=a2; d[3]=a3;
        *(uint*)&LX[0][xr*PAD + xc] = pack2(v.x, v.y);
    }

    f32x4 acc = {0.f,0.f,0.f,0.f};
    for (int c = 0; c < 8; ++c){
        bar_lds();
        int cur = c & 1, nxt = cur ^ 1;
        const uint4* sn = stage_src(c+1, WembB, WihaB, WihbB, wr2, wc2);
        uint4 r0=sn[0], r1=sn[1], r2=sn[2], r3=sn[3];
        float2 vx = {0.f,0.f};
        if (c+1 < 8) vx = *(const float2*)(x + (size_t)(R0 + xr)*DIN + (c+1)*128 + xc);
#pragma unroll
        for (int kb = 0; kb < 4; ++kb){
            bf16x8 a = *(const bf16x8*)&LX[cur][n*PAD + kb*32 + quad*8];
            bf16x8 b = *(const bf16x8*)&LW[cur][(wave*16 + n)*PAD + kb*32 + quad*8];
            acc = __builtin_amdgcn_mfma_f32_16x16x32_bf16(a, b, acc, 0,0,0);
        }
        {
            uint4* d = (uint4*)&LW[nxt][wr2*PAD + wc2];
            d[0]=r0; d[1]=r1; d[2]=r2; d[3]=r3;
            if (c+1 < 8) *(uint*)&LX[nxt][xr*PAD + xc] = pack2(vx.x, vx.y);
        }
    }
    if (quad < 2){
        int e = wave*16 + n;
        float wo = Wo[e];
#pragma unroll
        for (int l = 0; l < 4; ++l){
            int m = quad*4 + l;
            LE[m*PAD + e] = f2bf(acc[l]);
            int row = R0 + m, b_ = row >> 7, pos = row & 127;
            woE[((size_t)(pos*Bn + b_))*HH + e] = wo * acc[l];
        }
    }
    for (int c = 8; c < 14; ++c){
        bar_lds();
        int cur = c & 1, nxt = cur ^ 1;
        uint4 r0, r1, r2, r3;
        if (c < 13){
            const uint4* sn = stage_src(c+1, WembB, WihaB, WihbB, wr2, wc2);
            r0=sn[0]; r1=sn[1]; r2=sn[2]; r3=sn[3];
        }
        f32x4 gc = {0.f,0.f,0.f,0.f};
#pragma unroll
        for (int kb = 0; kb < 4; ++kb){
            bf16x8 a = *(const bf16x8*)&LE[n*PAD + kb*32 + quad*8];
            bf16x8 b = *(const bf16x8*)&LW[cur][(wave*16 + n)*PAD + kb*32 + quad*8];
            gc = __builtin_amdgcn_mfma_f32_16x16x32_bf16(a, b, gc, 0,0,0);
        }
        int nc = c - 8;
        int gband = (nc < 3) ? nc : nc - 3;
        int g = gband*128 + wave*16 + n;
        const float* bi = (nc < 3) ? biha : bihb;
        const float* bh = (nc < 3) ? bhha : bhhb;
        float bias = bi[g] + ((gband < 2) ? bh[g] : 0.f);
        float scale = (gband < 2) ? 0.5f : 1.f;
        float* dst = (nc < 3) ? gia : gib;
        int P = (3*wave + gband)*16 + n;
        if (quad < 2){
#pragma unroll
            for (int l = 0; l < 4; ++l){
                int row = R0 + quad*4 + l, b_ = row >> 7, pos = row & 127;
                dst[((size_t)(pos*Bn + b_))*G3 + P] = scale*(gc[l] + bias);
            }
        }
        if (c < 13){
            uint4* d = (uint4*)&LW[nxt][wr2*PAD + wc2];
            d[0]=r0; d[1]=r1; d[2]=r2; d[3]=r3;
        }
    }
}

// ============ GRU recurrence (R11 champion structure; gates in packed fp32).
template<int GT>
__device__ __forceinline__ void gru_body(
    const float* __restrict__ Whh, const float* __restrict__ bhh,
    const float* __restrict__ Wsc, const float* __restrict__ bsc,
    const float* __restrict__ Gi,  const float* __restrict__ WoE,
    float* __restrict__ outW, int i)
{
    __shared__ __align__(16) ushort HF[2][2048];   // h in B-frag order, dbuf
    __shared__ __align__(16) ushort BFm[2][2048];  // wbeta in B-frag order, dbuf (GT1)
    __shared__ __align__(16) float SQ[16][SQP];    // [chain][k] s or q
    int tid = threadIdx.x;
    int lane = tid & 63, wave = tid >> 6;
    int quad = lane >> 4, n = lane & 15;

    if (tid < 256) ((uint4*)HF[1])[tid] = (uint4){0,0,0,0};

    if (wave < 8){
        // ================= G-waves: gates only =================
        int u = wave, jb = u*16 + quad*4;
        bf16x8 afr[3][4];
#pragma unroll
        for (int g = 0; g < 3; ++g){
            const float* src = Whh + (size_t)(g*HH + u*16 + n)*HH;
            float s = (g < 2) ? 0.5f : 1.0f;   // fold 0.5 into r,z rows
#pragma unroll
            for (int kb = 0; kb < 4; ++kb){
                const float* p = src + kb*32 + quad*8;
                float4 a = *(const float4*)p, b2 = *(const float4*)(p+4);
                union { uint4 q; bf16x8 v; } cv;
                cv.q.x = pack2(s*a.x, s*a.y);   cv.q.y = pack2(s*a.z, s*a.w);
                cv.q.z = pack2(s*b2.x,s*b2.y); cv.q.w = pack2(s*b2.z,s*b2.w);
                afr[g][kb] = cv.v;
            }
        }
        f32x2 bh2p[2];
        bh2p[0] = (f32x2){bhh[2*HH + jb], bhh[2*HH + jb + 1]};
        bh2p[1] = (f32x2){bhh[2*HH + jb + 2], bhh[2*HH + jb + 3]};
        f32x2 h0 = {0.f,0.f}, h1 = {0.f,0.f};

        const float* gp = Gi + ((size_t)(i*Bn + n))*G3 + u*48 + quad*4;
        float4 pg0 = *(const float4*)(gp);
        float4 pg1 = *(const float4*)(gp + 16);
        float4 pg2 = *(const float4*)(gp + 32);
        bar_lds();

        for (int k = 0; k <= i; ++k){
            int pos = i - k;
            float4 g0 = pg0, g1 = pg1, g2 = pg2;
            int pnext = (pos > 0) ? pos - 1 : 0;
            const float* gp2 = Gi + ((size_t)(pnext*Bn + n))*G3 + u*48 + quad*4;
            pg0 = *(const float4*)(gp2);
            pg1 = *(const float4*)(gp2 + 16);
            pg2 = *(const float4*)(gp2 + 32);

            const ushort* HR = HF[(k+1)&1];
            f32x4 a0={0.f,0.f,0.f,0.f}, a1=a0, a2=a0;
#pragma unroll
            for (int kb = 0; kb < 4; ++kb){
                bf16x8 bfr = *(const bf16x8*)&HR[(64*kb + lane)*8];
                a0 = __builtin_amdgcn_mfma_f32_16x16x32_bf16(afr[0][kb], bfr, a0, 0,0,0);
                a1 = __builtin_amdgcn_mfma_f32_16x16x32_bf16(afr[1][kb], bfr, a1, 0,0,0);
                a2 = __builtin_amdgcn_mfma_f32_16x16x32_bf16(afr[2][kb], bfr, a2, 0,0,0);
            }
            // ---- packed gates (2 dims per f32x2)
#pragma unroll
            for (int p2 = 0; p2 < 2; ++p2){
                f32x2 gi0 = p2 ? (f32x2){g0.z,g0.w} : (f32x2){g0.x,g0.y};
                f32x2 gi1 = p2 ? (f32x2){g1.z,g1.w} : (f32x2){g1.x,g1.y};
                f32x2 gi2 = p2 ? (f32x2){g2.z,g2.w} : (f32x2){g2.x,g2.y};
                f32x2 a0p = p2 ? (f32x2){a0[2],a0[3]} : (f32x2){a0[0],a0[1]};
                f32x2 a1p = p2 ? (f32x2){a1[2],a1[3]} : (f32x2){a1[0],a1[1]};
                f32x2 a2p = p2 ? (f32x2){a2[2],a2[3]} : (f32x2){a2[0],a2[1]};
                f32x2 mr = clamp2(gi0 + a0p, -4.f, 4.f);
                f32x2 mz = clamp2(gi1 + a1p, -4.f, 4.f);
                f32x2 tr = mr*mr, tz = mz*mz;
                f32x2 nr = mr*(tr*(tr*(tr*0.5f + 189.f) + 8662.5f) + 67567.5f);
                f32x2 nz = mz*(tz*(tz*(tz*0.5f + 189.f) + 8662.5f) + 67567.5f);
                f32x2 dr = tr*(tr*(tr*28.f + 3150.f) + 62370.f) + 135135.f;
                f32x2 dz = tz*(tz*(tz*28.f + 3150.f) + 62370.f) + 135135.f;
                f32x2 rD = rcp2(dr*dz);
                f32x2 r = nr*dz*rD + 0.5f;
                f32x2 z = nz*dr*rD + 0.5f;
                f32x2 nn = tanh2(gi2 + r*(a2p + bh2p[p2]));
                if (p2 == 0) h0 = nn + z*(h0 - nn);
                else         h1 = nn + z*(h1 - nn);
            }
            *(uint2*)&HF[k&1][((jb>>3)*16 + n)*8 + (jb&4)] =
                (uint2){pack2(h0.x,h0.y), pack2(h1.x,h1.y)};
            bar_lds();
        }
        if (GT){ bar_lds(); bar_lds(); } else { bar_lds(); }
    } else {
        // ================= P-waves =================
        int u2 = wave - 8, jb = u2*16 + quad*4;
        if (GT){
            bf16x8 afr3[4];
#pragma unroll
            for (int kb = 0; kb < 4; ++kb){
                const float* p = Wsc + (size_t)(u2*16 + n)*HH + kb*32 + quad*8;
                float4 a = *(const float4*)p, b2 = *(const float4*)(p+4);
                union { uint4 q; bf16x8 v; } cv;
                cv.q.x = pack2(0.5f*a.x, 0.5f*a.y);  cv.q.y = pack2(0.5f*a.z, 0.5f*a.w);
                cv.q.z = pack2(0.5f*b2.x,0.5f*b2.y); cv.q.w = pack2(0.5f*b2.z,0.5f*b2.w);
                afr3[kb] = cv.v;
            }
            bf16x8 onesf;
            {
                union { uint4 q; bf16x8 v; } c1;
                uint o = (n == 0) ? 0x3F803F80u : 0u;
                c1.q = (uint4){o,o,o,o};
                onesf = c1.v;
            }
            f32x2 bb0 = {bsc[jb], bsc[jb+1]}, bb1 = {bsc[jb+2], bsc[jb+3]};
            float4 pwo = *(const float4*)(WoE + ((size_t)(i*Bn + n))*HH + jb);
            bar_lds();

            for (int k = 0; k <= i; ++k){
                int pos = i - k;
                float4 wo = pwo;
                pwo = *(const float4*)(WoE + ((size_t)(pos*Bn + n))*HH + jb);

                const ushort* HR = HF[(k+1)&1];
                f32x4 a3 = {0.f,0.f,0.f,0.f};
#pragma unroll
                for (int kb = 0; kb < 4; ++kb){
                    bf16x8 bfr = *(const bf16x8*)&HR[(64*kb + lane)*8];
                    a3 = __builtin_amdgcn_mfma_f32_16x16x32_bf16(afr3[kb], bfr, a3, 0,0,0);
                }
                if (u2 == 0 && k >= 2){   // q_{k-2} = ones . BF (written step k-1)
                    const ushort* BR = BFm[(k+1)&1];
                    f32x4 qa = {0.f,0.f,0.f,0.f};
#pragma unroll
                    for (int kb = 0; kb < 4; ++kb){
                        bf16x8 bq = *(const bf16x8*)&BR[(64*kb + lane)*8];
                        qa = __builtin_amdgcn_mfma_f32_16x16x32_bf16(onesf, bq, qa, 0,0,0);
                    }
                    if (lane < 16) SQ[lane][k-2] = qa[0];
                }
                if (k >= 1){
                    f32x2 w0 = tanh2((f32x2){a3[0],a3[1]} + bb0) * (f32x2){wo.x,wo.y};
                    f32x2 w1 = tanh2((f32x2){a3[2],a3[3]} + bb1) * (f32x2){wo.z,wo.w};
                    *(uint2*)&BFm[k&1][((jb>>3)*16 + n)*8 + (jb&4)] =
                        (uint2){pack2(w0.x,w0.y), pack2(w1.x,w1.y)};
                }
                bar_lds();
            }
            {   // tail: wbeta_i from h_i (HF[i&1]) with WoE[0] (in pwo)
                const ushort* HR = HF[i&1];
                f32x4 a3 = {0.f,0.f,0.f,0.f};
#pragma unroll
                for (int kb = 0; kb < 4; ++kb){
                    bf16x8 bfr = *(const bf16x8*)&HR[(64*kb + lane)*8];
                    a3 = __builtin_amdgcn_mfma_f32_16x16x32_bf16(afr3[kb], bfr, a3, 0,0,0);
                }
                f32x2 w0 = tanh2((f32x2){a3[0],a3[1]} + bb0) * (f32x2){pwo.x,pwo.y};
                f32x2 w1 = tanh2((f32x2){a3[2],a3[3]} + bb1) * (f32x2){pwo.z,pwo.w};
                *(uint2*)&BFm[(i+1)&1][((jb>>3)*16 + n)*8 + (jb&4)] =
                    (uint2){pack2(w0.x,w0.y), pack2(w1.x,w1.y)};
            }
            bar_lds();
            if (u2 == 0){
                if (i >= 1){
                    const ushort* BR = BFm[i&1];
                    f32x4 qa = {0.f,0.f,0.f,0.f};
#pragma unroll
                    for (int kb = 0; kb < 4; ++kb){
                        bf16x8 bq = *(const bf16x8*)&BR[(64*kb + lane)*8];
                        qa = __builtin_amdgcn_mfma_f32_16x16x32_bf16(onesf, bq, qa, 0,0,0);
                    }
                    if (lane < 16) SQ[lane][i-1] = qa[0];
                }
                {
                    const ushort* BR = BFm[(i+1)&1];
                    f32x4 qa = {0.f,0.f,0.f,0.f};
#pragma unroll
                    for (int kb = 0; kb < 4; ++kb){
                        bf16x8 bq = *(const bf16x8*)&BR[(64*kb + lane)*8];
                        qa = __builtin_amdgcn_mfma_f32_16x16x32_bf16(onesf, bq, qa, 0,0,0);
                    }
                    if (lane < 16) SQ[lane][i] = qa[0];
                }
            }
            bar_lds();
        } else {
            // GT0: wave 8 computes s_k = 0.5*Wa . h_k (A-row 0); waves 9-15 idle.
            if (u2 == 0){
                bf16x8 afr3[4];
#pragma unroll
                for (int kb = 0; kb < 4; ++kb){
                    const float* p = Wsc + kb*32 + quad*8;
                    float4 a = *(const float4*)p, b2 = *(const float4*)(p+4);
                    union { uint4 q; bf16x8 v; } cv;
                    if (n == 0){
                        cv.q.x = pack2(0.5f*a.x, 0.5f*a.y);  cv.q.y = pack2(0.5f*a.z, 0.5f*a.w);
                        cv.q.z = pack2(0.5f*b2.x,0.5f*b2.y); cv.q.w = pack2(0.5f*b2.z,0.5f*b2.w);
                    } else cv.q = (uint4){0,0,0,0};
                    afr3[kb] = cv.v;
                }
                float bav = bsc[0];
                bar_lds();
                for (int k = 0; k <= i; ++k){
                    if (k >= 1){   // s_{k-1} from h_{k-1} (HF[(k+1)&1])
                        const ushort* HR = HF[(k+1)&1];
                        f32x4 a3 = {0.f,0.f,0.f,0.f};
#pragma unroll
                        for (int kb = 0; kb < 4; ++kb){
                            bf16x8 bfr = *(const bf16x8*)&HR[(64*kb + lane)*8];
                            a3 = __builtin_amdgcn_mfma_f32_16x16x32_bf16(afr3[kb], bfr, a3, 0,0,0);
                        }
                        if (lane < 16) SQ[lane][k-1] = a3[0] + bav;
                    }
                    bar_lds();
                }
                {   // s_i from h_i
                    const ushort* HR = HF[i&1];
                    f32x4 a3 = {0.f,0.f,0.f,0.f};
#pragma unroll
                    for (int kb = 0; kb < 4; ++kb){
                        bf16x8 bfr = *(const bf16x8*)&HR[(64*kb + lane)*8];
                        a3 = __builtin_amdgcn_mfma_f32_16x16x32_bf16(afr3[kb], bfr, a3, 0,0,0);
                    }
                    if (lane < 16) SQ[lane][i] = a3[0] + bav;
                }
                bar_lds();
            } else {
                bar_lds();
                for (int k = 0; k <= i; ++k) bar_lds();
                bar_lds();
            }
        }
    }
    if (tid < 512){   // flush SQ -> global, coalesced float4 (k_out masks k > i)
        int cn = tid >> 5, k4 = (tid & 31) * 4;
        *(float4*)&outW[((size_t)(cn*Tn + i))*Tn + k4] = *(const float4*)&SQ[cn][k4];
    }
}

// grid = 256 linear; gt = blk & 1 so each XCD (id%8) hosts only one GRU type.
__global__ __launch_bounds__(1024, 1) void k_gru(
    const float* __restrict__ WhhA, const float* __restrict__ bhhA,
    const float* __restrict__ Wa,   const float* __restrict__ ba,
    const float* __restrict__ WhhB, const float* __restrict__ bhhB,
    const float* __restrict__ Wb,   const float* __restrict__ bb,
    const float* __restrict__ GiA,  const float* __restrict__ GiB,
    const float* __restrict__ WoE,
    float* __restrict__ sW, float* __restrict__ qW)
{
    int i = Tn - 1 - (blockIdx.x >> 1);
    if ((blockIdx.x & 1) == 0) gru_body<0>(WhhA, bhhA, Wa, ba, GiA, nullptr, sW, i);
    else                       gru_body<1>(WhhB, bhhB, Wb, bb, GiB, WoE,    qW, i);
}

// ============ softmax(s) . q per row; one wave per (b,i)
__global__ __launch_bounds__(256) void k_out(const float* __restrict__ sW,
                                             const float* __restrict__ qW,
                                             const float* __restrict__ bo,
                                             float* __restrict__ out){
    int tid = threadIdx.x, lane = tid & 63, w = tid >> 6;
    int r = blockIdx.x*4 + w;
    int i = r & (Tn-1);
    const float* s = sW + (size_t)r*Tn;
    const float* q = qW + (size_t)r*Tn;
    float s0 = (lane     <= i) ? s[lane]      : -1e30f;
    float s1 = (64+lane  <= i) ? s[64+lane]   : -1e30f;
    float m = fmaxf(s0, s1);
#pragma unroll
    for (int off = 32; off; off >>= 1) m = fmaxf(m, __shfl_xor(m, off));
    float e0 = __expf(s0 - m), e1 = __expf(s1 - m);
    float q0 = (lane    <= i) ? q[lane]    : 0.f;
    float q1 = (64+lane <= i) ? q[64+lane] : 0.f;
    float num = e0*q0 + e1*q1, den = e0 + e1;
#pragma unroll
    for (int off = 32; off; off >>= 1){
        num += __shfl_xor(num, off);
        den += __shfl_xor(den, off);
    }
    if (lane == 0) out[r] = num/den + bo[0];
}

extern "C" void kernel_launch(void* const* d_in, const int* in_sizes, int n_in,
                              void* d_out, int out_size, void* d_ws, size_t ws_size,
                              hipStream_t stream) {
    const float* x     = (const float*)d_in[0];
    const float* Wemb  = (const float*)d_in[1];
    const float* Wih_a = (const float*)d_in[2];
    const float* Whh_a = (const float*)d_in[3];
    const float* bih_a = (const float*)d_in[4];
    const float* bhh_a = (const float*)d_in[5];
    const float* Wa    = (const float*)d_in[6];
    const float* ba    = (const float*)d_in[7];
    const float* Wih_b = (const float*)d_in[8];
    const float* Whh_b = (const float*)d_in[9];
    const float* bih_b = (const float*)d_in[10];
    const float* bhh_b = (const float*)d_in[11];
    const float* Wb    = (const float*)d_in[12];
    const float* bb    = (const float*)d_in[13];
    const float* Wo    = (const float*)d_in[14];
    const float* bo    = (const float*)d_in[15];

    const int NR = Bn*Tn;                            // 2048 rows
    float* giA = (float*)d_ws;                       // [pos][b][384] fp32, P-permuted, r/z pre-scaled
    float* giB = giA + (size_t)NR*G3;
    float* woE = giB + (size_t)NR*G3;                // [pos][b][128] fp32
    float* sW  = woE + (size_t)NR*HH;                // [b][i][k] fp32
    float* qW  = sW + (size_t)NR*Tn;
    ushort* wcv = (ushort*)(qW + (size_t)NR*Tn);     // bf16: Wemb|Wiha|Wihb
    ushort* wembB = wcv;                             // 131072
    ushort* wihaB = wcv + 131072;                    // 49152
    ushort* wihbB = wcv + 180224;                    // 49152

    k_cvt<<<dim3(112), 256, 0, stream>>>(Wemb, Wih_a, Wih_b, wcv);
    k_embgi<<<dim3(256), 512, 0, stream>>>(x, wembB, wihaB, wihbB,
                                           bih_a, bhh_a, bih_b, bhh_b, Wo,
                                           giA, giB, woE);
    k_gru<<<dim3(256), 1024, 0, stream>>>(Whh_a, bhh_a, Wa, ba,
                                          Whh_b, bhh_b, Wb, bb,
                                          giA, giB, woE, sW, qW);
    k_out<<<dim3(NR/4), 256, 0, stream>>>(sW, qW, bo, (float*)d_out);
}